// Round 16
// baseline (64.304 us; speedup 1.0000x reference)
//
#include <hip/hip_runtime.h>

// Conv2D 3x3 VALID NHWC, B=16 H=W=224 C=32 F=32 -> [16,222,222,32] fp32.
// Round 16: R14 (wave-autonomous, 45.6us best) is limited by 2 waves/SIMD;
// R15 proved more registers/wave is unavailable (128-VGPR cap -> spill).
// So buy TLP instead: halve strip width to 32 cols. LDS/wave 16.9->8.7 KB,
// block 69.6 KB -> 2 blocks/CU = 4 waves/SIMD (double latency hiding).
// Work decode exact: 222 = 37 row-strips x RPW=6; 7 col-strips; 4144 waves
// = 518 blocks, ~all co-resident. VGPR ~110 (sv 20 regs) -- no spill.
// Same conflict-free 64B/px layout (stride 2176 = 0 mod 128B). m204
// bijective XCD remap for nwg=518 (q=64,r=6); rst-fastest order keeps
// vertical neighbors on one XCD for L2 halo reuse.

#define HO 222
#define WO 222
#define HIN 224
#define WIN 224
#define CIN 32
#define FOUT 32

#define RPW 6                 // output rows per wave-strip (37 x 6 = 222 exact)
#define SPX 34                // staged px per row (32 + 2 halo)
#define WROWB 2176            // 34 px * 64 B bf16
#define WAVELDS 8704          // 4 ring slots -> block 69632 B = 2 blocks/CU
#define NSG 5                 // stage granule-iters (272 granules / 64 lanes)

typedef __attribute__((ext_vector_type(8))) short short8;
typedef __attribute__((ext_vector_type(4))) float float4v;

__device__ inline short f2bf(float f) {                  // RNE (weights only)
    unsigned u = __builtin_bit_cast(unsigned, f);
    unsigned r = (u + 0x7FFFu + ((u >> 16) & 1u)) >> 16;
    return (short)r;
}

__global__ __launch_bounds__(512, 2) void conv3x3_wave(
    const float* __restrict__ x,     // [16,224,224,32]
    const float* __restrict__ w,     // [32][288 = (kh,kw,c)]
    const float* __restrict__ bias,  // [32]
    float* __restrict__ out)         // [16,222,222,32]
{
    __shared__ uint4 lds_all[8 * WAVELDS / 16];          // 69632 B
    const int tid  = threadIdx.x;
    const int lane = tid & 63;
    const int wave = tid >> 6;                           // 0..7
    char* wbase = reinterpret_cast<char*>(lds_all) + wave * WAVELDS;

    const int fcol = lane & 15;            // A row (filter) / D col (pixel)
    const int kq   = lane >> 4;            // k-slice: channels kq*8..+7

    // ---- weights -> register A-fragments ----
    short8 bfr[2][9];
#pragma unroll
    for (int h = 0; h < 2; ++h) {
        const float* wf = w + (h * 16 + fcol) * 288 + kq * 8;
#pragma unroll
        for (int s = 0; s < 9; ++s) {
            float4 lo = reinterpret_cast<const float4*>(wf + s * 32)[0];
            float4 hi = reinterpret_cast<const float4*>(wf + s * 32)[1];
            short8 v;
            v[0] = f2bf(lo.x); v[1] = f2bf(lo.y); v[2] = f2bf(lo.z); v[3] = f2bf(lo.w);
            v[4] = f2bf(hi.x); v[5] = f2bf(hi.y); v[6] = f2bf(hi.z); v[7] = f2bf(hi.w);
            bfr[h][s] = v;
        }
    }
    const float4 bias0 = reinterpret_cast<const float4*>(bias)[kq];
    const float4 bias1 = reinterpret_cast<const float4*>(bias)[4 + kq];

    // ---- m204 bijective XCD remap, nwg = 518 = 8*64 + 6 ----
    const int orig = blockIdx.x;
    const int xcd  = orig & 7;
    const int wid  = (xcd < 6 ? xcd * 65 : 6 * 65 + (xcd - 6) * 64) + (orig >> 3);

    // wave-strip id; rst fastest -> vertical neighbors contiguous on one XCD
    const int W    = wid * 8 + wave;       // 0..4143
    const int b    = W / 259;              // 7 colstrips * 37 rowstrips
    const int rem  = W - b * 259;
    const int cst  = rem / 37;             // 0..6
    const int rst  = rem - cst * 37;       // 0..36
    const int c0   = cst * 32;
    const int gr0  = rst * RPW;            // 0..216 (+7 staged <= 223: no row clamp)

    float4 sv[NSG];                        // stage registers (const-indexed)

#define SLOAD(RR)                                                             \
    {                                                                         \
        const int ir_ = gr0 + (RR);                                           \
        _Pragma("unroll")                                                     \
        for (int i_ = 0; i_ < NSG; ++i_) {                                    \
            int g_ = lane + 64 * i_; if (g_ > 271) g_ = 271;                  \
            int px_ = g_ >> 3, sub_ = g_ & 7;                                 \
            int ic_ = c0 + px_; if (ic_ > WIN - 1) ic_ = WIN - 1;             \
            sv[i_] = *reinterpret_cast<const float4*>(                        \
                x + ((b * HIN + ir_) * WIN + ic_) * CIN + sub_ * 4);          \
        }                                                                     \
    }

#define SWRITE(RR)                                                            \
    {                                                                         \
        char* sb_ = wbase + ((RR) & 3) * WROWB;                               \
        _Pragma("unroll")                                                     \
        for (int i_ = 0; i_ < NSG; ++i_) {                                    \
            int g_ = lane + 64 * i_; if (g_ > 271) g_ = 271;                  \
            int px_ = g_ >> 3, sub_ = g_ & 7;                                 \
            uint4 u_ = __builtin_bit_cast(uint4, sv[i_]);                     \
            uint2 p_;                                                         \
            p_.x = __builtin_amdgcn_perm(u_.y, u_.x, 0x07060302u);            \
            p_.y = __builtin_amdgcn_perm(u_.w, u_.z, 0x07060302u);            \
            *reinterpret_cast<uint2*>(sb_ + px_ * 64 + sub_ * 8) = p_;        \
        }                                                                     \
    }

    // ---------- prologue: rows 0,1,2 into ring slots 0,1,2 ----------
    SLOAD(0); SWRITE(0);
    SLOAD(1); SWRITE(1);
    SLOAD(2); SWRITE(2);

    // ---------- barrier-free main loop ----------
#pragma unroll 1
    for (int r = 0; r < RPW; ++r) {
        if (r < RPW - 1) SLOAD(r + 3);               // rows 3..7 in flight
        __builtin_amdgcn_sched_barrier(0);

        const int ho = gr0 + r;
#pragma unroll
        for (int ck = 0; ck < 2; ++ck) {
            float4v acc0 = {0.f, 0.f, 0.f, 0.f};
            float4v acc1 = {0.f, 0.f, 0.f, 0.f};
#pragma unroll
            for (int s = 0; s < 9; ++s) {
                const int kh = s / 3, kw = s % 3;
                const short8 a = *reinterpret_cast<const short8*>(
                    wbase + ((r + kh) & 3) * WROWB + (ck * 16 + fcol + kw) * 64 + kq * 16);
                acc0 = __builtin_amdgcn_mfma_f32_16x16x32_bf16(bfr[0][s], a, acc0, 0, 0, 0);
                acc1 = __builtin_amdgcn_mfma_f32_16x16x32_bf16(bfr[1][s], a, acc1, 0, 0, 0);
            }
            // D[filter][pixel]: col(lane&15)=pixel, row=kq*4+r=filter
            const int wo = c0 + ck * 16 + fcol;
            if (wo < WO) {
                float* o = out + ((b * HO + ho) * WO + wo) * FOUT;
                float4 v0 = {acc0[0] + bias0.x, acc0[1] + bias0.y,
                             acc0[2] + bias0.z, acc0[3] + bias0.w};
                float4 v1 = {acc1[0] + bias1.x, acc1[1] + bias1.y,
                             acc1[2] + bias1.z, acc1[3] + bias1.w};
                reinterpret_cast<float4*>(o)[kq]     = v0;
                reinterpret_cast<float4*>(o)[4 + kq] = v1;
            }
        }

        __builtin_amdgcn_sched_barrier(0);
        if (r < RPW - 1) SWRITE(r + 3);              // slot (r+3)&3 = (r-1)&3, consumed
    }
}

extern "C" void kernel_launch(void* const* d_in, const int* in_sizes, int n_in,
                              void* d_out, int out_size, void* d_ws, size_t ws_size,
                              hipStream_t stream) {
    const float* x    = (const float*)d_in[0];
    const float* w    = (const float*)d_in[1];
    const float* bias = (const float*)d_in[2];
    float* out        = (float*)d_out;

    conv3x3_wave<<<dim3(518), dim3(512), 0, stream>>>(x, w, bias, out);
}